// Round 4
// baseline (832.350 us; speedup 1.0000x reference)
//
#include <hip/hip_runtime.h>

// MultibandFrameAttention: B=1, W=2048, BINS=1024, BANDS=16, d=64, CROP=2048, K=3
// Pipeline: cast/transpose -> fused QKV GEMM (f16 MFMA) -> depthwise conv ->
// flash attention (qk write + online softmax + PV) -> output GEMM.
// Key identity: the pad/transpose/slice bias == (q @ relw)^T, i.e. one extra MFMA
// with relwT rows as A-operand and Q rows as B-operand.

#define W_ 2048
#define BINS_ 1024
#define H_ 16
#define D_ 64

typedef _Float16 f16x8 __attribute__((ext_vector_type(8)));
typedef _Float16 f16x4 __attribute__((ext_vector_type(4)));
typedef float f32x4_t __attribute__((ext_vector_type(4)));

#define MFMA16(A, B, C) __builtin_amdgcn_mfma_f32_16x16x32_f16((A), (B), (C), 0, 0, 0)

// ---------------- elementwise cast fp32 -> f16 (vectorized x4) ----------------
__global__ __launch_bounds__(256) void cast_f16_kernel(const float* __restrict__ in,
                                                       _Float16* __restrict__ out, int n) {
    int i = (blockIdx.x * 256 + threadIdx.x) * 4;
    if (i + 3 < n) {
        float4 v = *(const float4*)(in + i);
        f16x4 o;
        o[0] = (_Float16)v.x; o[1] = (_Float16)v.y;
        o[2] = (_Float16)v.z; o[3] = (_Float16)v.w;
        *(f16x4*)(out + i) = o;
    }
}

// ---------------- transpose+cast: in (R x C) fp32 -> out (C x R) f16 ----------------
__global__ __launch_bounds__(256) void transpose_cast_kernel(const float* __restrict__ in,
                                                             _Float16* __restrict__ out,
                                                             int R, int C) {
    __shared__ float tile[32][33];
    const int tx = threadIdx.x, ty = threadIdx.y;
    const int r0 = blockIdx.y * 32, c0 = blockIdx.x * 32;
#pragma unroll
    for (int i = 0; i < 4; i++)
        tile[ty * 4 + i][tx] = in[(size_t)(r0 + ty * 4 + i) * C + c0 + tx];
    __syncthreads();
#pragma unroll
    for (int i = 0; i < 4; i++)
        out[(size_t)(c0 + ty * 4 + i) * R + r0 + tx] = (_Float16)tile[tx][ty * 4 + i];
}

// ---------------- GEMM: C[M x N] = A[M x K] * Bt[N x K]^T, f16 in, fp32 out ----------------
// 128x128 tile, BK=64, 4 waves in 2x2, 16x16x32 f16 MFMA. LDS rows padded to 72 halves.
__global__ __launch_bounds__(256, 2) void gemm_f16_kernel(const _Float16* __restrict__ A,
                                                          const _Float16* __restrict__ Bt,
                                                          float* __restrict__ C,
                                                          int M, int N, int K, int ldc) {
    __shared__ __align__(16) _Float16 As[128][72];
    __shared__ __align__(16) _Float16 Bs[128][72];
    const int tid = threadIdx.x;
    const int wave = tid >> 6, lane = tid & 63, l15 = lane & 15, q4 = lane >> 4;
    const int m0 = blockIdx.y * 128, n0 = blockIdx.x * 128;
    const int wm = (wave & 1) * 64, wn = (wave >> 1) * 64;
    const f32x4_t vzero = {0.f, 0.f, 0.f, 0.f};
    f32x4_t acc[4][4];
#pragma unroll
    for (int i = 0; i < 4; i++)
#pragma unroll
        for (int j = 0; j < 4; j++) acc[i][j] = vzero;

    for (int k0 = 0; k0 < K; k0 += 64) {
        __syncthreads();
#pragma unroll
        for (int it = 0; it < 4; it++) {
            int flat = it * 256 + tid;
            int row = flat >> 3, k8 = (flat & 7) * 8;
            *(f16x8*)&As[row][k8] = *(const f16x8*)(A + (size_t)(m0 + row) * K + k0 + k8);
            *(f16x8*)&Bs[row][k8] = *(const f16x8*)(Bt + (size_t)(n0 + row) * K + k0 + k8);
        }
        __syncthreads();
#pragma unroll
        for (int kc = 0; kc < 2; kc++) {
            f16x8 af[4], bf[4];
#pragma unroll
            for (int i = 0; i < 4; i++) af[i] = *(const f16x8*)&As[wm + i * 16 + l15][kc * 32 + q4 * 8];
#pragma unroll
            for (int j = 0; j < 4; j++) bf[j] = *(const f16x8*)&Bs[wn + j * 16 + l15][kc * 32 + q4 * 8];
#pragma unroll
            for (int i = 0; i < 4; i++)
#pragma unroll
                for (int j = 0; j < 4; j++) acc[i][j] = MFMA16(af[i], bf[j], acc[i][j]);
        }
    }
    // C/D layout: col = lane&15, row = (lane>>4)*4 + r  [m89/m91 verified]
#pragma unroll
    for (int i = 0; i < 4; i++)
#pragma unroll
        for (int j = 0; j < 4; j++)
#pragma unroll
            for (int r = 0; r < 4; r++)
                C[(size_t)(m0 + wm + i * 16 + q4 * 4 + r) * ldc + n0 + wn + j * 16 + l15] = acc[i][j][r];
}

// ---------------- depthwise conv (K=3, pad 1) over w; emits Qb/Kb (h,w,d) and Vt (h,d,w) f16 ----------------
__global__ __launch_bounds__(256) void conv_qkv_kernel(const float* __restrict__ tmp,
                                                       const float* __restrict__ cq,
                                                       const float* __restrict__ ck,
                                                       const float* __restrict__ cv,
                                                       _Float16* __restrict__ Qb,
                                                       _Float16* __restrict__ Kb,
                                                       _Float16* __restrict__ Vt) {
    const int h = blockIdx.y, wt = blockIdx.x;
    const int tid = threadIdx.x;
    const int dl = tid & 63;   // d within head
    const int wr = tid >> 6;   // row group 0..3
    const int c = h * 64 + dl; // global channel
    __shared__ float vtile[64][65];
    const float q0w = cq[c * 3], q1w = cq[c * 3 + 1], q2w = cq[c * 3 + 2];
    const float k0w = ck[c * 3], k1w = ck[c * 3 + 1], k2w = ck[c * 3 + 2];
    const float v0w = cv[c * 3], v1w = cv[c * 3 + 1], v2w = cv[c * 3 + 2];
    for (int it = 0; it < 16; ++it) {
        const int wl = it * 4 + wr;
        const int w = wt * 64 + wl;
        const float* row = tmp + (size_t)w * 3072;
        const bool hm = (w > 0), hp = (w < W_ - 1);
        float qa = hm ? row[c - 3072] : 0.f;
        float qb_ = row[c];
        float qc = hp ? row[c + 3072] : 0.f;
        float ka = hm ? row[1024 + c - 3072] : 0.f;
        float kb_ = row[1024 + c];
        float kc = hp ? row[1024 + c + 3072] : 0.f;
        float va = hm ? row[2048 + c - 3072] : 0.f;
        float vb_ = row[2048 + c];
        float vc = hp ? row[2048 + c + 3072] : 0.f;
        Qb[((size_t)h * W_ + w) * D_ + dl] = (_Float16)(qa * q0w + qb_ * q1w + qc * q2w);
        Kb[((size_t)h * W_ + w) * D_ + dl] = (_Float16)(ka * k0w + kb_ * k1w + kc * k2w);
        vtile[wl][dl] = va * v0w + vb_ * v1w + vc * v2w;
    }
    __syncthreads();
    // write V transposed (h, d, w) — conflict-free: bank = (w_local + d) % 32
    for (int it = 0; it < 16; ++it) {
        const int d = it * 4 + wr;
        Vt[((size_t)h * D_ + d) * W_ + wt * 64 + dl] = (_Float16)vtile[dl][d];
    }
}

// ---------------- flash attention: qk write + online softmax + PV ----------------
// grid = 512 x 256 (4 waves). Round-0 compute core; memory-pattern changes only:
//  * prev is staged via LDS: per 128-col j-tile each wave loads its 16 rows as
//    8 x float4 instructions, each covering two CONTIGUOUS 512B row-chunks
//    (vs 4 scattered 64B sectors) -> DRAM page locality.
//  * loads are issued into regs BEFORE the S-MFMA block (~1000cy of independent
//    work) and written to LDS after -> HBM latency hidden without compiler luck.
//  * qk stores are nontemporal: the 268MB single-use write stream must not
//    evict prev / K/Q/V from L2/L3.
//  * one softmax rescale per 128 cols (was per 64).
__global__ __launch_bounds__(256, 2) void flash_kernel(const _Float16* __restrict__ Qb,
                                                       const _Float16* __restrict__ Kb,
                                                       const _Float16* __restrict__ Vt,
                                                       const _Float16* __restrict__ relT,
                                                       const float* __restrict__ prev,
                                                       float* __restrict__ qkout,
                                                       _Float16* __restrict__ obuf) {
    const int tid = threadIdx.x;
    const int wave = tid >> 6, lane = tid & 63, l15 = lane & 15, q4 = lane >> 4;
    const int b = blockIdx.x;
    const int h = (b & 7) * 2 + ((b >> 3) & 1); // 2 heads per XCD
    const int ib = b >> 4;                      // 0..31
    const int i0 = ib * 64;
    const int wrow0 = i0 + wave * 16;           // this wave's 16 q-rows
    const _Float16* Qh = Qb + (size_t)h * W_ * D_;
    const _Float16* Kh = Kb + (size_t)h * W_ * D_;
    const _Float16* Vh = Vt + (size_t)h * D_ * W_;
    const float* prevh = prev + (size_t)h * W_ * W_;
    float* qkh = qkout + (size_t)h * W_ * W_;

    // persistent A-frags: Q rows (for S1) and relwT rows (for the bias MFMA S2)
    // A layout: A[m = lane&15][k = (lane>>4)*8 + j]  [m120 verified]
    f16x8 qfrag[2], rfrag[2];
    {
        const int r = wrow0 + l15;
        qfrag[0] = *(const f16x8*)(Qh + (size_t)r * D_ + q4 * 8);
        qfrag[1] = *(const f16x8*)(Qh + (size_t)r * D_ + 32 + q4 * 8);
        rfrag[0] = *(const f16x8*)(relT + (size_t)r * D_ + q4 * 8);
        rfrag[1] = *(const f16x8*)(relT + (size_t)r * D_ + 32 + q4 * 8);
    }
    const f32x4_t vzero = {0.f, 0.f, 0.f, 0.f};
    f32x4_t Oacc[4];
#pragma unroll
    for (int dt = 0; dt < 4; dt++) Oacc[dt] = vzero;
    float m_i[4] = {-1e30f, -1e30f, -1e30f, -1e30f};
    float l_i[4] = {0.f, 0.f, 0.f, 0.f};
    // per-wave private P tile, stride 72 halves to de-conflict b128 reads
    __shared__ __align__(16) _Float16 pbuf[4][16][72];
    // per-wave prev staging tile: 16 rows x 128 cols fp32, stride 132 (132%32=4
    // -> scalar reads are only 2-way bank-aliased = free)
    __shared__ __align__(16) float pstage[4][16][132];
    const int irow0 = wrow0 + q4 * 4;
    const float scale = 0.03125f; // 1/sqrt(1024)
    // staging lane map: instr i covers rows i*2+(lane>>5), cols (lane&31)*4
    const int srow = lane >> 5, scol = (lane & 31) * 4;
    const float* psrc = prevh + (size_t)(wrow0 + srow) * W_ + scol;
    float* qkrow = qkh + (size_t)irow0 * W_;

    for (int j0 = 0; j0 < W_; j0 += 128) {
        // ---- (a) issue prev staging loads: 8 x float4, each 2 contiguous 512B chunks ----
        float4 pld[8];
#pragma unroll
        for (int i = 0; i < 8; i++)
            pld[i] = *(const float4*)(psrc + (size_t)(i * 2) * W_ + j0);

        // ---- (b) S = Qi*Kj^T + relwT_i*Qj^T for 2 sub-tiles (128 cols) ----
        f32x4_t acc[2][4];
#pragma unroll
        for (int sub = 0; sub < 2; sub++)
#pragma unroll
            for (int ct = 0; ct < 4; ct++) {
                const int jc = j0 + sub * 64 + ct * 16 + l15;
                const _Float16* kr = Kh + (size_t)jc * D_ + q4 * 8;
                const _Float16* qr = Qh + (size_t)jc * D_ + q4 * 8;
                f32x4_t a = vzero;
                a = MFMA16(qfrag[0], *(const f16x8*)kr, a);
                a = MFMA16(rfrag[0], *(const f16x8*)qr, a);
                a = MFMA16(qfrag[1], *(const f16x8*)(kr + 32), a);
                a = MFMA16(rfrag[1], *(const f16x8*)(qr + 32), a);
                acc[sub][ct] = a;
            }

        // ---- (c) park staged prev in LDS (loads have landed under (b)) ----
#pragma unroll
        for (int i = 0; i < 8; i++)
            *(float4*)&pstage[wave][i * 2 + srow][scol] = pld[i];

        // ---- (d) v = S*scale + prev; nontemporal qk store; row max ----
        float tmax[4] = {-3e38f, -3e38f, -3e38f, -3e38f};
#pragma unroll
        for (int sub = 0; sub < 2; sub++)
#pragma unroll
            for (int ct = 0; ct < 4; ct++) {
                const int col = sub * 64 + ct * 16 + l15;
                float* qq = qkrow + j0 + col;
#pragma unroll
                for (int r = 0; r < 4; r++) {
                    float v = acc[sub][ct][r] * scale + pstage[wave][q4 * 4 + r][col];
                    __builtin_nontemporal_store(v, qq + (size_t)r * W_);
                    acc[sub][ct][r] = v;
                    tmax[r] = fmaxf(tmax[r], v);
                }
            }
        // row max across the 16 lanes sharing a row (xor 1,2,4,8 stays inside l&15 group)
#pragma unroll
        for (int r = 0; r < 4; r++) {
            float t = tmax[r];
            t = fmaxf(t, __shfl_xor(t, 1, 64));
            t = fmaxf(t, __shfl_xor(t, 2, 64));
            t = fmaxf(t, __shfl_xor(t, 4, 64));
            t = fmaxf(t, __shfl_xor(t, 8, 64));
            tmax[r] = fmaxf(m_i[r], t);
        }
        float alpha[4];
#pragma unroll
        for (int r = 0; r < 4; r++) {
            alpha[r] = __expf(m_i[r] - tmax[r]);
            m_i[r] = tmax[r];
        }
#pragma unroll
        for (int dt = 0; dt < 4; dt++) {
            Oacc[dt][0] *= alpha[0];
            Oacc[dt][1] *= alpha[1];
            Oacc[dt][2] *= alpha[2];
            Oacc[dt][3] *= alpha[3];
        }
        // ---- (e) exp, P->LDS->A-layout, PV per 64-col sub-tile ----
        float rsum[4] = {0.f, 0.f, 0.f, 0.f};
#pragma unroll
        for (int sub = 0; sub < 2; sub++) {
#pragma unroll
            for (int ct = 0; ct < 4; ct++)
#pragma unroll
                for (int r = 0; r < 4; r++) {
                    float p = __expf(acc[sub][ct][r] - m_i[r]);
                    rsum[r] += p;
                    pbuf[wave][q4 * 4 + r][ct * 16 + l15] = (_Float16)p;
                }
#pragma unroll
            for (int kc = 0; kc < 2; kc++) {
                f16x8 pf = *(const f16x8*)&pbuf[wave][l15][kc * 32 + q4 * 8];
#pragma unroll
                for (int dt = 0; dt < 4; dt++) {
                    f16x8 vf = *(const f16x8*)(Vh + (size_t)(dt * 16 + l15) * W_ +
                                               j0 + sub * 64 + kc * 32 + q4 * 8);
                    Oacc[dt] = MFMA16(pf, vf, Oacc[dt]);
                }
            }
        }
#pragma unroll
        for (int r = 0; r < 4; r++) {
            float t = rsum[r];
            t += __shfl_xor(t, 1, 64);
            t += __shfl_xor(t, 2, 64);
            t += __shfl_xor(t, 4, 64);
            t += __shfl_xor(t, 8, 64);
            l_i[r] = l_i[r] * alpha[r] + t;
        }
    }
    // epilogue: normalize and emit o in (w, h*64+d) f16 layout for the Wo GEMM
#pragma unroll
    for (int r = 0; r < 4; r++) {
        const float inv = 1.f / l_i[r];
        const int ig = irow0 + r;
#pragma unroll
        for (int dt = 0; dt < 4; dt++)
            obuf[(size_t)ig * BINS_ + h * 64 + dt * 16 + l15] = (_Float16)(Oacc[dt][r] * inv);
    }
}

// ---------------- host launch ----------------
extern "C" void kernel_launch(void* const* d_in, const int* in_sizes, int n_in,
                              void* d_out, int out_size, void* d_ws, size_t ws_size,
                              hipStream_t stream) {
    const float* x = (const float*)d_in[0];
    const float* prev = (const float*)d_in[1];
    const float* Wq = (const float*)d_in[2];
    const float* Wk = (const float*)d_in[3];
    const float* Wv = (const float*)d_in[4];
    const float* Wo = (const float*)d_in[5];
    const float* cq = (const float*)d_in[6];
    const float* ck = (const float*)d_in[7];
    const float* cv = (const float*)d_in[8];
    const float* relw = (const float*)d_in[9];
    float* out0 = (float*)d_out;                  // (2048, 1024) fp32
    float* qk = out0 + (size_t)W_ * BINS_;        // (16, 2048, 2048) fp32

    // workspace map (needs ~53 MiB)
    char* wsb = (char*)d_ws;
    _Float16* xb = (_Float16*)(wsb);                        // 2048x1024 f16   (4 MiB)
    _Float16* WtA = (_Float16*)(wsb + (4u << 20));          // 3072x1024 f16   (6 MiB)
    _Float16* Wot = (_Float16*)(wsb + (10u << 20));         // 1024x1024 f16   (2 MiB)
    _Float16* relT = (_Float16*)(wsb + (12u << 20));        // 2048x64 f16     (256 KiB)
    _Float16* Qb = (_Float16*)(wsb + (13u << 20));          // (16,2048,64)    (4 MiB)
    _Float16* Kb = (_Float16*)(wsb + (17u << 20));          // (16,2048,64)    (4 MiB)
    _Float16* Vt = (_Float16*)(wsb + (21u << 20));          // (16,64,2048)    (4 MiB)
    _Float16* obuf = (_Float16*)(wsb + (25u << 20));        // (2048,1024)     (4 MiB)
    float* tmp = (float*)(wsb + (29u << 20));               // (2048,3072) fp32 (24 MiB)

    cast_f16_kernel<<<2048, 256, 0, stream>>>(x, xb, W_ * BINS_);
    dim3 tb(32, 8);
    transpose_cast_kernel<<<dim3(32, 32), tb, 0, stream>>>(Wq, WtA, 1024, 1024);
    transpose_cast_kernel<<<dim3(32, 32), tb, 0, stream>>>(Wk, WtA + 1024 * 1024, 1024, 1024);
    transpose_cast_kernel<<<dim3(32, 32), tb, 0, stream>>>(Wv, WtA + 2 * 1024 * 1024, 1024, 1024);
    transpose_cast_kernel<<<dim3(64, 2), tb, 0, stream>>>(relw, relT, 64, 2048);
    // fused QKV GEMM: (2048x1024) @ (1024x3072) -> tmp
    gemm_f16_kernel<<<dim3(24, 16), 256, 0, stream>>>(xb, WtA, tmp, 2048, 3072, 1024, 3072);
    conv_qkv_kernel<<<dim3(32, 16), 256, 0, stream>>>(tmp, cq, ck, cv, Qb, Kb, Vt);
    flash_kernel<<<512, 256, 0, stream>>>(Qb, Kb, Vt, relT, prev, qk, obuf);
    // out0 = o @ Wo
    gemm_f16_kernel<<<dim3(8, 16), 256, 0, stream>>>(obuf, Wot, out0, 2048, 1024, 1024, 1024);
}

// Round 5
// 672.552 us; speedup vs baseline: 1.2376x; 1.2376x over previous
//
#include <hip/hip_runtime.h>

// MultibandFrameAttention: B=1, W=2048, BINS=1024, BANDS=16, d=64, CROP=2048, K=3
// Pipeline: cast/transpose -> fused QKV GEMM (f16 MFMA) -> depthwise conv ->
// flash attention (qk write + online softmax + PV) -> output GEMM.
// Key identity: the pad/transpose/slice bias == (q @ relw)^T, i.e. one extra MFMA
// with relwT rows as A-operand and Q rows as B-operand.

#define W_ 2048
#define BINS_ 1024
#define H_ 16
#define D_ 64

typedef _Float16 f16x8 __attribute__((ext_vector_type(8)));
typedef _Float16 f16x4 __attribute__((ext_vector_type(4)));
typedef float f32x4_t __attribute__((ext_vector_type(4)));

#define MFMA16(A, B, C) __builtin_amdgcn_mfma_f32_16x16x32_f16((A), (B), (C), 0, 0, 0)

// ---------------- elementwise cast fp32 -> f16 (vectorized x4) ----------------
__global__ __launch_bounds__(256) void cast_f16_kernel(const float* __restrict__ in,
                                                       _Float16* __restrict__ out, int n) {
    int i = (blockIdx.x * 256 + threadIdx.x) * 4;
    if (i + 3 < n) {
        float4 v = *(const float4*)(in + i);
        f16x4 o;
        o[0] = (_Float16)v.x; o[1] = (_Float16)v.y;
        o[2] = (_Float16)v.z; o[3] = (_Float16)v.w;
        *(f16x4*)(out + i) = o;
    }
}

// ---------------- transpose+cast: in (R x C) fp32 -> out (C x R) f16 ----------------
__global__ __launch_bounds__(256) void transpose_cast_kernel(const float* __restrict__ in,
                                                             _Float16* __restrict__ out,
                                                             int R, int C) {
    __shared__ float tile[32][33];
    const int tx = threadIdx.x, ty = threadIdx.y;
    const int r0 = blockIdx.y * 32, c0 = blockIdx.x * 32;
#pragma unroll
    for (int i = 0; i < 4; i++)
        tile[ty * 4 + i][tx] = in[(size_t)(r0 + ty * 4 + i) * C + c0 + tx];
    __syncthreads();
#pragma unroll
    for (int i = 0; i < 4; i++)
        out[(size_t)(c0 + ty * 4 + i) * R + r0 + tx] = (_Float16)tile[tx][ty * 4 + i];
}

// ---------------- GEMM: C[M x N] = A[M x K] * Bt[N x K]^T, f16 in, fp32 out ----------------
// 128x128 tile, BK=64, 4 waves in 2x2, 16x16x32 f16 MFMA. LDS rows padded to 72 halves.
__global__ __launch_bounds__(256, 2) void gemm_f16_kernel(const _Float16* __restrict__ A,
                                                          const _Float16* __restrict__ Bt,
                                                          float* __restrict__ C,
                                                          int M, int N, int K, int ldc) {
    __shared__ __align__(16) _Float16 As[128][72];
    __shared__ __align__(16) _Float16 Bs[128][72];
    const int tid = threadIdx.x;
    const int wave = tid >> 6, lane = tid & 63, l15 = lane & 15, q4 = lane >> 4;
    const int m0 = blockIdx.y * 128, n0 = blockIdx.x * 128;
    const int wm = (wave & 1) * 64, wn = (wave >> 1) * 64;
    const f32x4_t vzero = {0.f, 0.f, 0.f, 0.f};
    f32x4_t acc[4][4];
#pragma unroll
    for (int i = 0; i < 4; i++)
#pragma unroll
        for (int j = 0; j < 4; j++) acc[i][j] = vzero;

    for (int k0 = 0; k0 < K; k0 += 64) {
        __syncthreads();
#pragma unroll
        for (int it = 0; it < 4; it++) {
            int flat = it * 256 + tid;
            int row = flat >> 3, k8 = (flat & 7) * 8;
            *(f16x8*)&As[row][k8] = *(const f16x8*)(A + (size_t)(m0 + row) * K + k0 + k8);
            *(f16x8*)&Bs[row][k8] = *(const f16x8*)(Bt + (size_t)(n0 + row) * K + k0 + k8);
        }
        __syncthreads();
#pragma unroll
        for (int kc = 0; kc < 2; kc++) {
            f16x8 af[4], bf[4];
#pragma unroll
            for (int i = 0; i < 4; i++) af[i] = *(const f16x8*)&As[wm + i * 16 + l15][kc * 32 + q4 * 8];
#pragma unroll
            for (int j = 0; j < 4; j++) bf[j] = *(const f16x8*)&Bs[wn + j * 16 + l15][kc * 32 + q4 * 8];
#pragma unroll
            for (int i = 0; i < 4; i++)
#pragma unroll
                for (int j = 0; j < 4; j++) acc[i][j] = MFMA16(af[i], bf[j], acc[i][j]);
        }
    }
    // C/D layout: col = lane&15, row = (lane>>4)*4 + r  [m89/m91 verified]
#pragma unroll
    for (int i = 0; i < 4; i++)
#pragma unroll
        for (int j = 0; j < 4; j++)
#pragma unroll
            for (int r = 0; r < 4; r++)
                C[(size_t)(m0 + wm + i * 16 + q4 * 4 + r) * ldc + n0 + wn + j * 16 + l15] = acc[i][j][r];
}

// ---------------- depthwise conv (K=3, pad 1) over w; emits Qb/Kb (h,w,d) and Vt (h,d,w) f16 ----------------
__global__ __launch_bounds__(256) void conv_qkv_kernel(const float* __restrict__ tmp,
                                                       const float* __restrict__ cq,
                                                       const float* __restrict__ ck,
                                                       const float* __restrict__ cv,
                                                       _Float16* __restrict__ Qb,
                                                       _Float16* __restrict__ Kb,
                                                       _Float16* __restrict__ Vt) {
    const int h = blockIdx.y, wt = blockIdx.x;
    const int tid = threadIdx.x;
    const int dl = tid & 63;   // d within head
    const int wr = tid >> 6;   // row group 0..3
    const int c = h * 64 + dl; // global channel
    __shared__ float vtile[64][65];
    const float q0w = cq[c * 3], q1w = cq[c * 3 + 1], q2w = cq[c * 3 + 2];
    const float k0w = ck[c * 3], k1w = ck[c * 3 + 1], k2w = ck[c * 3 + 2];
    const float v0w = cv[c * 3], v1w = cv[c * 3 + 1], v2w = cv[c * 3 + 2];
    for (int it = 0; it < 16; ++it) {
        const int wl = it * 4 + wr;
        const int w = wt * 64 + wl;
        const float* row = tmp + (size_t)w * 3072;
        const bool hm = (w > 0), hp = (w < W_ - 1);
        float qa = hm ? row[c - 3072] : 0.f;
        float qb_ = row[c];
        float qc = hp ? row[c + 3072] : 0.f;
        float ka = hm ? row[1024 + c - 3072] : 0.f;
        float kb_ = row[1024 + c];
        float kc = hp ? row[1024 + c + 3072] : 0.f;
        float va = hm ? row[2048 + c - 3072] : 0.f;
        float vb_ = row[2048 + c];
        float vc = hp ? row[2048 + c + 3072] : 0.f;
        Qb[((size_t)h * W_ + w) * D_ + dl] = (_Float16)(qa * q0w + qb_ * q1w + qc * q2w);
        Kb[((size_t)h * W_ + w) * D_ + dl] = (_Float16)(ka * k0w + kb_ * k1w + kc * k2w);
        vtile[wl][dl] = va * v0w + vb_ * v1w + vc * v2w;
    }
    __syncthreads();
    // write V transposed (h, d, w) — conflict-free: bank = (w_local + d) % 32
    for (int it = 0; it < 16; ++it) {
        const int d = it * 4 + wr;
        Vt[((size_t)h * D_ + d) * W_ + wt * 64 + dl] = (_Float16)vtile[dl][d];
    }
}

// ---------------- flash attention: qk write + online softmax + PV ----------------
// grid = 512: XCD-swizzled so each head's K/Q/V stays in one XCD's L2.
// Each wg: 64 q-rows of one head; each wave 16 rows; j-tiles of 64.
// Load-ordering fix (vmcnt is a FIFO): per tile, issue the 16 K/Q fragment
// loads FIRST, then the 16 prev loads, then the MFMA chain. MFMAs wait only on
// the older K/Q loads (L2-fast) via vmcnt(N>=16); the prev loads stay in
// flight and land under the MFMA block, so the +prev phase has ~no exposed HBM
// latency. sched_barrier(0) x2 pins the two load batches' FIFO order.
// (R1/R4 lesson: issuing prev BEFORE K/Q forces every MFMA wait to drain
// prev's ~900cy HBM latency first -> serialization, 272->304/415us.)
__global__ __launch_bounds__(256, 2) void flash_kernel(const _Float16* __restrict__ Qb,
                                                       const _Float16* __restrict__ Kb,
                                                       const _Float16* __restrict__ Vt,
                                                       const _Float16* __restrict__ relT,
                                                       const float* __restrict__ prev,
                                                       float* __restrict__ qkout,
                                                       _Float16* __restrict__ obuf) {
    const int tid = threadIdx.x;
    const int wave = tid >> 6, lane = tid & 63, l15 = lane & 15, q4 = lane >> 4;
    const int b = blockIdx.x;
    const int h = (b & 7) * 2 + ((b >> 3) & 1); // 2 heads per XCD
    const int ib = b >> 4;                      // 0..31
    const int i0 = ib * 64;
    const _Float16* Qh = Qb + (size_t)h * W_ * D_;
    const _Float16* Kh = Kb + (size_t)h * W_ * D_;
    const _Float16* Vh = Vt + (size_t)h * D_ * W_;
    const float* prevh = prev + (size_t)h * W_ * W_;
    float* qkh = qkout + (size_t)h * W_ * W_;

    // persistent A-frags: Q rows (for S1) and relwT rows (for the bias MFMA S2)
    // A layout: A[m = lane&15][k = (lane>>4)*8 + j]  [m120 verified]
    f16x8 qfrag[2], rfrag[2];
    {
        const int r = i0 + wave * 16 + l15;
        qfrag[0] = *(const f16x8*)(Qh + (size_t)r * D_ + q4 * 8);
        qfrag[1] = *(const f16x8*)(Qh + (size_t)r * D_ + 32 + q4 * 8);
        rfrag[0] = *(const f16x8*)(relT + (size_t)r * D_ + q4 * 8);
        rfrag[1] = *(const f16x8*)(relT + (size_t)r * D_ + 32 + q4 * 8);
    }
    const f32x4_t vzero = {0.f, 0.f, 0.f, 0.f};
    f32x4_t Oacc[4];
#pragma unroll
    for (int dt = 0; dt < 4; dt++) Oacc[dt] = vzero;
    float m_i[4] = {-1e30f, -1e30f, -1e30f, -1e30f};
    float l_i[4] = {0.f, 0.f, 0.f, 0.f};
    // per-wave private P tile, stride 72 halves to de-conflict b128 reads
    __shared__ __align__(16) _Float16 pbuf[4][16][72];
    const int irow0 = i0 + wave * 16 + q4 * 4;
    const float scale = 0.03125f; // 1/sqrt(1024)
    const float* prow = prevh + (size_t)irow0 * W_ + l15;
    float* qkrow = qkh + (size_t)irow0 * W_ + l15;

    for (int j0 = 0; j0 < W_; j0 += 64) {
        // ---- (1) batch K/Q fragment loads (16 x 16B, L2-resident) ----
        f16x8 kf0[4], kf1[4], qf0[4], qf1[4];
#pragma unroll
        for (int ct = 0; ct < 4; ct++) {
            const _Float16* kr = Kh + (size_t)(j0 + ct * 16 + l15) * D_ + q4 * 8;
            const _Float16* qr = Qh + (size_t)(j0 + ct * 16 + l15) * D_ + q4 * 8;
            kf0[ct] = *(const f16x8*)kr;
            kf1[ct] = *(const f16x8*)(kr + 32);
            qf0[ct] = *(const f16x8*)qr;
            qf1[ct] = *(const f16x8*)(qr + 32);
        }
        __builtin_amdgcn_sched_barrier(0);
        // ---- (2) issue prev loads (16 x 4B, HBM) AFTER K/Q in the vmem FIFO ----
        float pv[16];
#pragma unroll
        for (int ct = 0; ct < 4; ct++)
#pragma unroll
            for (int r = 0; r < 4; r++)
                pv[ct * 4 + r] = prow[(size_t)r * W_ + j0 + ct * 16];
        __builtin_amdgcn_sched_barrier(0);
        // ---- (3) S = Qi*Kj^T + relwT_i*Qj^T : waits only on K/Q (older loads) ----
        f32x4_t acc[4];
#pragma unroll
        for (int ct = 0; ct < 4; ct++) {
            f32x4_t a = vzero;
            a = MFMA16(qfrag[0], kf0[ct], a);
            a = MFMA16(rfrag[0], qf0[ct], a);
            a = MFMA16(qfrag[1], kf1[ct], a);
            a = MFMA16(rfrag[1], qf1[ct], a);
            acc[ct] = a;
        }
        // ---- (4) scale, + prev (landed under MFMAs), write qk, track row max ----
        float tmax[4] = {-3e38f, -3e38f, -3e38f, -3e38f};
#pragma unroll
        for (int ct = 0; ct < 4; ct++) {
            float* qq = qkrow + j0 + ct * 16;
#pragma unroll
            for (int r = 0; r < 4; r++) {
                float v = acc[ct][r] * scale + pv[ct * 4 + r];
                qq[(size_t)r * W_] = v;
                acc[ct][r] = v;
                tmax[r] = fmaxf(tmax[r], v);
            }
        }
        // row max across the 16 lanes sharing a row (xor 1,2,4,8 stays inside l&15 group)
#pragma unroll
        for (int r = 0; r < 4; r++) {
            float t = tmax[r];
            t = fmaxf(t, __shfl_xor(t, 1, 64));
            t = fmaxf(t, __shfl_xor(t, 2, 64));
            t = fmaxf(t, __shfl_xor(t, 4, 64));
            t = fmaxf(t, __shfl_xor(t, 8, 64));
            tmax[r] = fmaxf(m_i[r], t);
        }
        float alpha[4];
#pragma unroll
        for (int r = 0; r < 4; r++) {
            alpha[r] = __expf(m_i[r] - tmax[r]);
            m_i[r] = tmax[r];
        }
        float rsum[4] = {0.f, 0.f, 0.f, 0.f};
#pragma unroll
        for (int ct = 0; ct < 4; ct++)
#pragma unroll
            for (int r = 0; r < 4; r++) {
                float p = __expf(acc[ct][r] - m_i[r]);
                acc[ct][r] = p;
                rsum[r] += p;
            }
#pragma unroll
        for (int r = 0; r < 4; r++) {
            float t = rsum[r];
            t += __shfl_xor(t, 1, 64);
            t += __shfl_xor(t, 2, 64);
            t += __shfl_xor(t, 4, 64);
            t += __shfl_xor(t, 8, 64);
            l_i[r] = l_i[r] * alpha[r] + t;
        }
#pragma unroll
        for (int dt = 0; dt < 4; dt++) {
            Oacc[dt][0] *= alpha[0];
            Oacc[dt][1] *= alpha[1];
            Oacc[dt][2] *= alpha[2];
            Oacc[dt][3] *= alpha[3];
        }
        // P: C-layout -> LDS -> A-layout (m120 pattern)
#pragma unroll
        for (int ct = 0; ct < 4; ct++)
#pragma unroll
            for (int r = 0; r < 4; r++)
                pbuf[wave][q4 * 4 + r][ct * 16 + l15] = (_Float16)acc[ct][r];
        __syncthreads();
#pragma unroll
        for (int kc = 0; kc < 2; kc++) {
            f16x8 pf = *(const f16x8*)&pbuf[wave][l15][kc * 32 + q4 * 8];
#pragma unroll
            for (int dt = 0; dt < 4; dt++) {
                f16x8 vf = *(const f16x8*)(Vh + (size_t)(dt * 16 + l15) * W_ + j0 + kc * 32 + q4 * 8);
                Oacc[dt] = MFMA16(pf, vf, Oacc[dt]);
            }
        }
    }
    // epilogue: normalize and emit o in (w, h*64+d) f16 layout for the Wo GEMM
#pragma unroll
    for (int r = 0; r < 4; r++) {
        const float inv = 1.f / l_i[r];
        const int ig = irow0 + r;
#pragma unroll
        for (int dt = 0; dt < 4; dt++)
            obuf[(size_t)ig * BINS_ + h * 64 + dt * 16 + l15] = (_Float16)(Oacc[dt][r] * inv);
    }
}

// ---------------- host launch ----------------
extern "C" void kernel_launch(void* const* d_in, const int* in_sizes, int n_in,
                              void* d_out, int out_size, void* d_ws, size_t ws_size,
                              hipStream_t stream) {
    const float* x = (const float*)d_in[0];
    const float* prev = (const float*)d_in[1];
    const float* Wq = (const float*)d_in[2];
    const float* Wk = (const float*)d_in[3];
    const float* Wv = (const float*)d_in[4];
    const float* Wo = (const float*)d_in[5];
    const float* cq = (const float*)d_in[6];
    const float* ck = (const float*)d_in[7];
    const float* cv = (const float*)d_in[8];
    const float* relw = (const float*)d_in[9];
    float* out0 = (float*)d_out;                  // (2048, 1024) fp32
    float* qk = out0 + (size_t)W_ * BINS_;        // (16, 2048, 2048) fp32

    // workspace map (needs ~53 MiB)
    char* wsb = (char*)d_ws;
    _Float16* xb = (_Float16*)(wsb);                        // 2048x1024 f16   (4 MiB)
    _Float16* WtA = (_Float16*)(wsb + (4u << 20));          // 3072x1024 f16   (6 MiB)
    _Float16* Wot = (_Float16*)(wsb + (10u << 20));         // 1024x1024 f16   (2 MiB)
    _Float16* relT = (_Float16*)(wsb + (12u << 20));        // 2048x64 f16     (256 KiB)
    _Float16* Qb = (_Float16*)(wsb + (13u << 20));          // (16,2048,64)    (4 MiB)
    _Float16* Kb = (_Float16*)(wsb + (17u << 20));          // (16,2048,64)    (4 MiB)
    _Float16* Vt = (_Float16*)(wsb + (21u << 20));          // (16,64,2048)    (4 MiB)
    _Float16* obuf = (_Float16*)(wsb + (25u << 20));        // (2048,1024)     (4 MiB)
    float* tmp = (float*)(wsb + (29u << 20));               // (2048,3072) fp32 (24 MiB)

    cast_f16_kernel<<<2048, 256, 0, stream>>>(x, xb, W_ * BINS_);
    dim3 tb(32, 8);
    transpose_cast_kernel<<<dim3(32, 32), tb, 0, stream>>>(Wq, WtA, 1024, 1024);
    transpose_cast_kernel<<<dim3(32, 32), tb, 0, stream>>>(Wk, WtA + 1024 * 1024, 1024, 1024);
    transpose_cast_kernel<<<dim3(32, 32), tb, 0, stream>>>(Wv, WtA + 2 * 1024 * 1024, 1024, 1024);
    transpose_cast_kernel<<<dim3(64, 2), tb, 0, stream>>>(relw, relT, 64, 2048);
    // fused QKV GEMM: (2048x1024) @ (1024x3072) -> tmp
    gemm_f16_kernel<<<dim3(24, 16), 256, 0, stream>>>(xb, WtA, tmp, 2048, 3072, 1024, 3072);
    conv_qkv_kernel<<<dim3(32, 16), 256, 0, stream>>>(tmp, cq, ck, cv, Qb, Kb, Vt);
    flash_kernel<<<512, 256, 0, stream>>>(Qb, Kb, Vt, relT, prev, qk, obuf);
    // out0 = o @ Wo
    gemm_f16_kernel<<<dim3(8, 16), 256, 0, stream>>>(obuf, Wot, out0, 2048, 1024, 1024, 1024);
}